// Round 1
// baseline (80.394 us; speedup 1.0000x reference)
//
#include <hip/hip_runtime.h>
#include <hip/hip_bf16.h>

#define NB   64
#define NREG 4
#define ND   768
#define NH   37
#define NW   37
#define NC   5              // 1 + NREG cues
#define NP   (NH * NW)      // 1369
#define BPB  22             // blocks per batch for the sim kernel
#define PPB  ((NP + BPB - 1) / BPB)  // 63 patches per block

// Map float -> unsigned int preserving order (total order, -inf .. +inf)
__device__ __forceinline__ unsigned int ord_of(float f) {
    unsigned int u = __float_as_uint(f);
    return (u & 0x80000000u) ? ~u : (u | 0x80000000u);
}

__global__ void init_keys_kernel(unsigned long long* __restrict__ keys) {
    int i = blockIdx.x * blockDim.x + threadIdx.x;
    if (i < NB * NC) keys[i] = 0ull;
}

// One wave per patch per iteration: 5 cue dot-products + wave argmax.
__global__ __launch_bounds__(256) void sim_argmax_kernel(
    const float* __restrict__ cls_tok,
    const float* __restrict__ regs,
    const float* __restrict__ patches,
    unsigned long long* __restrict__ keys)
{
    const int b    = blockIdx.x / BPB;
    const int pb   = blockIdx.x % BPB;
    const int wave = threadIdx.x >> 6;
    const int lane = threadIdx.x & 63;

    // Preload this lane's slice of all 5 cues into registers (15 float4).
    float4 cue[NC][3];
    #pragma unroll
    for (int c = 0; c < NC; ++c) {
        const float* cb = (c == 0) ? (cls_tok + (size_t)b * ND)
                                   : (regs + ((size_t)b * NREG + (c - 1)) * ND);
        #pragma unroll
        for (int k = 0; k < 3; ++k)
            cue[c][k] = *reinterpret_cast<const float4*>(cb + k * 256 + lane * 4);
    }

    float best[NC];
    int   bidx[NC];
    #pragma unroll
    for (int c = 0; c < NC; ++c) { best[c] = -3.4e38f; bidx[c] = 0; }

    const int p0 = pb * PPB;
    const int p1 = min(NP, p0 + PPB);

    for (int p = p0 + wave; p < p1; p += 4) {
        const float* pbase = patches + ((size_t)b * NP + p) * ND;
        float s[NC] = {0.f, 0.f, 0.f, 0.f, 0.f};
        #pragma unroll
        for (int k = 0; k < 3; ++k) {
            float4 v = *reinterpret_cast<const float4*>(pbase + k * 256 + lane * 4);
            #pragma unroll
            for (int c = 0; c < NC; ++c) {
                s[c] += v.x * cue[c][k].x + v.y * cue[c][k].y
                      + v.z * cue[c][k].z + v.w * cue[c][k].w;
            }
        }
        #pragma unroll
        for (int c = 0; c < NC; ++c) {
            #pragma unroll
            for (int off = 32; off > 0; off >>= 1)
                s[c] += __shfl_xor(s[c], off, 64);
            if (s[c] > best[c]) { best[c] = s[c]; bidx[c] = p; }
        }
    }

    // All lanes of a wave agree after the butterfly; lane 0 publishes.
    if (lane == 0 && (p0 + wave) < p1) {
        #pragma unroll
        for (int c = 0; c < NC; ++c) {
            unsigned long long key =
                ((unsigned long long)ord_of(best[c]) << 32) |
                (unsigned long long)(unsigned)(NP - 1 - bidx[c]);  // low idx wins ties
            atomicMax(&keys[b * NC + c], key);
        }
    }
}

// One block per (b, cue): clipped-window mean + normalize cue & roi tokens.
__global__ __launch_bounds__(256) void roi_norm_kernel(
    const float* __restrict__ cls_tok,
    const float* __restrict__ regs,
    const float* __restrict__ patches,
    const unsigned long long* __restrict__ keys,
    const int* __restrict__ roi_side_p,
    float* __restrict__ out)
{
    const int b   = blockIdx.x / NC;
    const int c   = blockIdx.x % NC;
    const int tid = threadIdx.x;
    const int wave = tid >> 6, lane = tid & 63;
    const int r = roi_side_p[0] >> 1;

    const unsigned long long key = keys[b * NC + c];
    const int idx = NP - 1 - (int)(key & 0xFFFFFFFFu);
    const int hh = idx / NW, ww = idx % NW;
    const int h0 = max(0, hh - r), h1 = min(NH - 1, hh + r);
    const int w0 = max(0, ww - r), w1 = min(NW - 1, ww + r);
    const float inv_cnt = 1.0f / (float)((h1 - h0 + 1) * (w1 - w0 + 1));

    float a0 = 0.f, a1 = 0.f, a2 = 0.f;
    for (int h = h0; h <= h1; ++h) {
        for (int w = w0; w <= w1; ++w) {
            const float* p = patches + ((size_t)b * NP + h * NW + w) * ND;
            a0 += p[tid];
            a1 += p[tid + 256];
            a2 += p[tid + 512];
        }
    }
    a0 *= inv_cnt; a1 *= inv_cnt; a2 *= inv_cnt;

    const float* cb = (c == 0) ? (cls_tok + (size_t)b * ND)
                               : (regs + ((size_t)b * NREG + (c - 1)) * ND);
    const float v0 = cb[tid], v1 = cb[tid + 256], v2 = cb[tid + 512];

    // Block-reduce two sums of squares (cue, roi).
    float sx = v0 * v0 + v1 * v1 + v2 * v2;
    float sy = a0 * a0 + a1 * a1 + a2 * a2;
    #pragma unroll
    for (int off = 32; off > 0; off >>= 1) {
        sx += __shfl_xor(sx, off, 64);
        sy += __shfl_xor(sy, off, 64);
    }
    __shared__ float red_x[4], red_y[4];
    if (lane == 0) { red_x[wave] = sx; red_y[wave] = sy; }
    __syncthreads();
    const float tot_x = red_x[0] + red_x[1] + red_x[2] + red_x[3];
    const float tot_y = red_y[0] + red_y[1] + red_y[2] + red_y[3];
    const float inv_nc = 1.0f / fmaxf(sqrtf(tot_x), 1e-12f);
    const float inv_nr = 1.0f / fmaxf(sqrtf(tot_y), 1e-12f);

    float* oc = out + ((size_t)b * 2 * NC + c) * ND;       // cue token
    float* om = out + ((size_t)b * 2 * NC + NC + c) * ND;  // roi token
    oc[tid]       = v0 * inv_nc;
    oc[tid + 256] = v1 * inv_nc;
    oc[tid + 512] = v2 * inv_nc;
    om[tid]       = a0 * inv_nr;
    om[tid + 256] = a1 * inv_nr;
    om[tid + 512] = a2 * inv_nr;
}

extern "C" void kernel_launch(void* const* d_in, const int* in_sizes, int n_in,
                              void* d_out, int out_size, void* d_ws, size_t ws_size,
                              hipStream_t stream) {
    const float* cls_tok = (const float*)d_in[0];
    const float* regs    = (const float*)d_in[1];
    const float* patches = (const float*)d_in[2];
    const int*   roi     = (const int*)d_in[3];
    float* out = (float*)d_out;
    unsigned long long* keys = (unsigned long long*)d_ws;

    init_keys_kernel<<<1, 512, 0, stream>>>(keys);
    sim_argmax_kernel<<<NB * BPB, 256, 0, stream>>>(cls_tok, regs, patches, keys);
    roi_norm_kernel<<<NB * NC, 256, 0, stream>>>(cls_tok, regs, patches, keys, roi, out);
}

// Round 2
// 59.357 us; speedup vs baseline: 1.3544x; 1.3544x over previous
//
#include <hip/hip_runtime.h>
#include <hip/hip_bf16.h>

#define NB   64
#define NREG 4
#define ND   768
#define NH   37
#define NW   37
#define NC   5              // 1 + NREG cues
#define NP   (NH * NW)      // 1369
#define BPB  16             // blocks per batch -> 64*16 = 1024 blocks = 4/CU exactly
#define PPB  ((NP + BPB - 1) / BPB)  // 86 patches per block

// Map float -> unsigned int preserving order (total order, -inf .. +inf)
__device__ __forceinline__ unsigned int ord_of(float f) {
    unsigned int u = __float_as_uint(f);
    return (u & 0x80000000u) ? ~u : (u | 0x80000000u);
}

// One wave per patch per iteration: 5 cue dot-products + wave argmax.
// Each block writes NC partial keys (max over its patch range) to ws.
__global__ __launch_bounds__(256, 4) void sim_argmax_kernel(
    const float* __restrict__ cls_tok,
    const float* __restrict__ regs,
    const float* __restrict__ patches,
    unsigned long long* __restrict__ pkeys)
{
    const int b    = blockIdx.x / BPB;
    const int pb   = blockIdx.x % BPB;
    const int wave = threadIdx.x >> 6;
    const int lane = threadIdx.x & 63;

    // Preload this lane's slice of all 5 cues into registers (15 float4).
    float4 cue[NC][3];
    #pragma unroll
    for (int c = 0; c < NC; ++c) {
        const float* cb = (c == 0) ? (cls_tok + (size_t)b * ND)
                                   : (regs + ((size_t)b * NREG + (c - 1)) * ND);
        #pragma unroll
        for (int k = 0; k < 3; ++k)
            cue[c][k] = *reinterpret_cast<const float4*>(cb + k * 256 + lane * 4);
    }

    float best[NC];
    int   bidx[NC];
    #pragma unroll
    for (int c = 0; c < NC; ++c) { best[c] = -3.4e38f; bidx[c] = 0; }

    const int pstart = pb * PPB;
    const int p1     = min(NP, pstart + PPB);

    int p = pstart + wave;
    if (p < p1) {
        const float* base = patches + ((size_t)b * NP + p) * ND + lane * 4;
        float4 v0 = *reinterpret_cast<const float4*>(base);
        float4 v1 = *reinterpret_cast<const float4*>(base + 256);
        float4 v2 = *reinterpret_cast<const float4*>(base + 512);

        while (true) {
            const int pn = p + 4;
            const bool more = pn < p1;
            float4 n0, n1, n2;
            if (more) {  // issue next patch's loads before the reduce chain
                const float* nb = patches + ((size_t)b * NP + pn) * ND + lane * 4;
                n0 = *reinterpret_cast<const float4*>(nb);
                n1 = *reinterpret_cast<const float4*>(nb + 256);
                n2 = *reinterpret_cast<const float4*>(nb + 512);
            }

            float s[NC] = {0.f, 0.f, 0.f, 0.f, 0.f};
            #pragma unroll
            for (int c = 0; c < NC; ++c) {
                s[c] += v0.x * cue[c][0].x + v0.y * cue[c][0].y
                      + v0.z * cue[c][0].z + v0.w * cue[c][0].w;
                s[c] += v1.x * cue[c][1].x + v1.y * cue[c][1].y
                      + v1.z * cue[c][1].z + v1.w * cue[c][1].w;
                s[c] += v2.x * cue[c][2].x + v2.y * cue[c][2].y
                      + v2.z * cue[c][2].z + v2.w * cue[c][2].w;
            }
            #pragma unroll
            for (int c = 0; c < NC; ++c) {
                #pragma unroll
                for (int off = 32; off > 0; off >>= 1)
                    s[c] += __shfl_xor(s[c], off, 64);
                if (s[c] > best[c]) { best[c] = s[c]; bidx[c] = p; }
            }

            if (!more) break;
            v0 = n0; v1 = n1; v2 = n2; p = pn;
        }
    }

    // Combine the 4 waves' bests in LDS, then one plain store per cue.
    __shared__ unsigned long long lk[4][NC];
    if (lane == 0) {
        #pragma unroll
        for (int c = 0; c < NC; ++c) {
            lk[wave][c] =
                ((unsigned long long)ord_of(best[c]) << 32) |
                (unsigned long long)(unsigned)(NP - 1 - bidx[c]);  // low idx wins ties
        }
    }
    __syncthreads();
    if (threadIdx.x < NC) {
        unsigned long long k = lk[0][threadIdx.x];
        k = max(k, lk[1][threadIdx.x]);
        k = max(k, lk[2][threadIdx.x]);
        k = max(k, lk[3][threadIdx.x]);
        pkeys[(b * NC + threadIdx.x) * BPB + pb] = k;
    }
}

// One block per (b, cue): reduce partial keys, clipped-window mean,
// normalize cue & roi tokens.
__global__ __launch_bounds__(256) void roi_norm_kernel(
    const float* __restrict__ cls_tok,
    const float* __restrict__ regs,
    const float* __restrict__ patches,
    const unsigned long long* __restrict__ pkeys,
    const int* __restrict__ roi_side_p,
    float* __restrict__ out)
{
    const int b   = blockIdx.x / NC;
    const int c   = blockIdx.x % NC;
    const int tid = threadIdx.x;
    const int wave = tid >> 6, lane = tid & 63;
    const int r = roi_side_p[0] >> 1;

    // All threads redundantly reduce the BPB partial keys (uniform loads).
    const unsigned long long* pk = pkeys + (b * NC + c) * BPB;
    unsigned long long key = pk[0];
    #pragma unroll
    for (int i = 1; i < BPB; ++i) key = max(key, pk[i]);

    const int idx = NP - 1 - (int)(key & 0xFFFFFFFFu);
    const int hh = idx / NW, ww = idx % NW;
    const int h0 = max(0, hh - r), h1 = min(NH - 1, hh + r);
    const int w0 = max(0, ww - r), w1 = min(NW - 1, ww + r);
    const float inv_cnt = 1.0f / (float)((h1 - h0 + 1) * (w1 - w0 + 1));

    float a0 = 0.f, a1 = 0.f, a2 = 0.f;
    for (int h = h0; h <= h1; ++h) {
        for (int w = w0; w <= w1; ++w) {
            const float* p = patches + ((size_t)b * NP + h * NW + w) * ND;
            a0 += p[tid];
            a1 += p[tid + 256];
            a2 += p[tid + 512];
        }
    }
    a0 *= inv_cnt; a1 *= inv_cnt; a2 *= inv_cnt;

    const float* cb = (c == 0) ? (cls_tok + (size_t)b * ND)
                               : (regs + ((size_t)b * NREG + (c - 1)) * ND);
    const float v0 = cb[tid], v1 = cb[tid + 256], v2 = cb[tid + 512];

    // Block-reduce two sums of squares (cue, roi).
    float sx = v0 * v0 + v1 * v1 + v2 * v2;
    float sy = a0 * a0 + a1 * a1 + a2 * a2;
    #pragma unroll
    for (int off = 32; off > 0; off >>= 1) {
        sx += __shfl_xor(sx, off, 64);
        sy += __shfl_xor(sy, off, 64);
    }
    __shared__ float red_x[4], red_y[4];
    if (lane == 0) { red_x[wave] = sx; red_y[wave] = sy; }
    __syncthreads();
    const float tot_x = red_x[0] + red_x[1] + red_x[2] + red_x[3];
    const float tot_y = red_y[0] + red_y[1] + red_y[2] + red_y[3];
    const float inv_nc = 1.0f / fmaxf(sqrtf(tot_x), 1e-12f);
    const float inv_nr = 1.0f / fmaxf(sqrtf(tot_y), 1e-12f);

    float* oc = out + ((size_t)b * 2 * NC + c) * ND;       // cue token
    float* om = out + ((size_t)b * 2 * NC + NC + c) * ND;  // roi token
    oc[tid]       = v0 * inv_nc;
    oc[tid + 256] = v1 * inv_nc;
    oc[tid + 512] = v2 * inv_nc;
    om[tid]       = a0 * inv_nr;
    om[tid + 256] = a1 * inv_nr;
    om[tid + 512] = a2 * inv_nr;
}

extern "C" void kernel_launch(void* const* d_in, const int* in_sizes, int n_in,
                              void* d_out, int out_size, void* d_ws, size_t ws_size,
                              hipStream_t stream) {
    const float* cls_tok = (const float*)d_in[0];
    const float* regs    = (const float*)d_in[1];
    const float* patches = (const float*)d_in[2];
    const int*   roi     = (const int*)d_in[3];
    float* out = (float*)d_out;
    unsigned long long* pkeys = (unsigned long long*)d_ws;

    sim_argmax_kernel<<<NB * BPB, 256, 0, stream>>>(cls_tok, regs, patches, pkeys);
    roi_norm_kernel<<<NB * NC, 256, 0, stream>>>(cls_tok, regs, patches, pkeys, roi, out);
}